// Round 4
// baseline (119.813 us; speedup 1.0000x reference)
//
#include <hip/hip_runtime.h>
#include <hip/hip_fp16.h>
#include <stdint.h>

#define N 512
#define NA 180
#define PP 708          // padded image pitch (in 8B quad texels)
#define PR 704          // padded image rows
#define POFF 96         // padded index of image row/col 0

// d_ws float-offsets. Quad image = 708*704 uint2 = 996864 floats per variant.
#define WS_IMGQ   0
#define WS_IMGQT  (PR * PP * 2)             // 996864
#define WS_TAB    (2 * PR * PP * 2)         // 1993728 (16B aligned)
#define WS_FLAGS  (WS_TAB + 4 * NA)

typedef _Float16 hh2 __attribute__((ext_vector_type(2)));
union H2U { uint32_t u; hh2 h; };

__device__ __forceinline__ hh2 cvt_pkrtz(float a, float b) {
    return __builtin_bit_cast(hh2, __builtin_amdgcn_cvt_pkrtz(a, b));
}

__device__ __forceinline__ uint32_t packh2(float a, float b) {
    __half2 h = __halves2half2(__float2half(a), __float2half(b));
    return *(uint32_t*)&h;
}

// Tiled pad: 22x22 blocks of 32x32. Builds QUAD fp16 images: one 8B texel at
// (r,c) holds the full 2x2 bilinear footprint:
//   imgQ [r][c] = (P[r][c], P[r+1][c], P[r][c+1], P[r+1][c+1])     (P = padded img)
//   imgQT[r][c] = same for P^T
// lo dword = left column (top,bottom) pair, hi dword = right column pair, so a
// bilinear sample is ONE aligned global_load_dwordx2 + two v_dot2_f32_f16.
// Also writes the per-angle affine table. All global accesses coalesced.
__global__ __launch_bounds__(256) void pad_kernel(const float* __restrict__ img,
                                                  const int* __restrict__ angles,
                                                  uint2* __restrict__ imgQ,
                                                  uint2* __restrict__ imgQT,
                                                  float4* __restrict__ tab,
                                                  int* __restrict__ flags) {
    __shared__ float lds[33 * 34];   // pitch 34 (2-way LDS aliasing only - free)
    const int tid = threadIdx.x;
    const int bx = blockIdx.x, by = blockIdx.y;

    if (bx == 0 && by == 0 && tid < NA) {
        float t = (float)angles[tid] * 0.017453292519943295f;
        float si = sinf(t), co = cosf(t);
        int useT = fabsf(si) > fabsf(co);
        float4 e;
        if (useT) { e.x = co; e.y = -si; e.z = si; e.w = co; }
        else      { e.x = si; e.y = co;  e.z = co; e.w = -si; }
        tab[tid] = e;                // (au, bus, av, bvs)
        flags[tid] = useT;
    }

    // stage 33x33 of the padded image: padded coords (by*32+r, bx*32+c)
    for (int idx = tid; idx < 33 * 33; idx += 256) {
        int r = idx / 33, cc = idx - r * 33;
        int y = by * 32 + r - POFF, x = bx * 32 + cc - POFF;
        bool in = ((unsigned)y < N) && ((unsigned)x < N);
        lds[r * 34 + cc] = in ? img[y * N + x] : 0.0f;
    }
    __syncthreads();
    const int r0 = tid >> 5, cl = tid & 31;
#pragma unroll
    for (int j = 0; j < 4; ++j) {
        int row = j * 8 + r0;
        // quad of P at (by*32+row, bx*32+cl)
        uint2 qv;
        qv.x = packh2(lds[row * 34 + cl],     lds[(row + 1) * 34 + cl]);
        qv.y = packh2(lds[row * 34 + cl + 1], lds[(row + 1) * 34 + cl + 1]);
        imgQ[(size_t)(by * 32 + row) * PP + bx * 32 + cl] = qv;
        // quad of P^T at (bx*32+row, by*32+cl): PT[R][C] = P[C][R]
        uint2 qt;
        qt.x = packh2(lds[cl * 34 + row],       lds[cl * 34 + row + 1]);
        qt.y = packh2(lds[(cl + 1) * 34 + row], lds[(cl + 1) * 34 + row + 1]);
        imgQT[(size_t)(bx * 32 + row) * PP + by * 32 + cl] = qt;
    }
}

// Direct-from-L2/LLC radon, quad texels, 2-D wave footprint.
// Block = 256 thr = 4 waves; wave = 8 detectors x 8 parallel i-offsets
// (lane: dd = lane>>3, ii = lane&7). Each thread walks i = iLo+ii, step 8,
// over its per-ray analytic clip range (loose, apron-safe). One 8B quad load
// + 2 fdot2 per sample; no LDS, no barriers; 3 shfl_xor merge the 8 i-lanes.
// The 8x8 footprint bounds a wave-load's touched rows by 7(|si|+|co|)+2 <= 12
// (vs up to 46 with 64 flat detector lanes), cutting L1-tag serialization.
__global__ __launch_bounds__(256) void radon_kernel(const uint2* __restrict__ imgQ,
                                                    const uint2* __restrict__ imgQT,
                                                    const float4* __restrict__ tab,
                                                    const int* __restrict__ flags,
                                                    float* __restrict__ out) {
    const int tid  = threadIdx.x;
    const int lane = tid & 63;
    const int wave = tid >> 6;           // 0..3
    const int dd   = lane >> 3;          // 0..7 : detector within wave
    const int ii   = lane & 7;           // 0..7 : i-offset within wave
    const int a    = blockIdx.y;
    const int d    = blockIdx.x * 32 + wave * 8 + dd;

    const float c = 255.5f;
    const float4 tb = tab[a];
    const float au = tb.x, bus = tb.y, av = tb.z, bvs = tb.w;
    const uint2* __restrict__ src = flags[a] ? imgQT : imgQ;

    // per-ray affine in PADDED coords: u(i) = au*i + buP == au*(i-c) + bus*(d-c) + c + POFF
    const float xcl = (float)d - c;
    const float buP = fmaf(bus, xcl, c + (float)POFF) - au * c;
    const float bvP = fmaf(bvs, xcl, c + (float)POFF) - av * c;

    // loose live box [94, 609] in padded coords (true nonzero box (95,608)).
    // Kept samples have u,v in [93.99, 609.01] -> taps in rows/cols [93, 611],
    // strictly inside the written 0..703 region; apron taps are exactly 0.
    int iLo = 0, iHi = N - 1;
    if (fabsf(au) > 1e-6f) {
        float ia = 1.0f / au;
        float t0 = (94.0f - buP) * ia, t1 = (609.0f - buP) * ia;
        float lo = fminf(t0, t1), hi = fmaxf(t0, t1);
        iLo = max(iLo, (int)ceilf(lo));
        iHi = min(iHi, (int)floorf(hi));
    } else if (buP < 94.0f || buP > 609.0f) {
        iHi = iLo - 1;
    }
    if (fabsf(av) > 1e-6f) {
        float ia = 1.0f / av;
        float t0 = (94.0f - bvP) * ia, t1 = (609.0f - bvP) * ia;
        float lo = fminf(t0, t1), hi = fmaxf(t0, t1);
        iLo = max(iLo, (int)ceilf(lo));
        iHi = min(iHi, (int)floorf(hi));
    } else if (bvP < 94.0f || bvP > 609.0f) {
        iHi = iLo - 1;
    }

    float s = 0.0f;
    float fi = (float)(iLo + ii);        // integers <= 512: exact in fp32
    for (int i = iLo + ii; i <= iHi; i += 8) {
        float u = fmaf(au, fi, buP);     // fresh fmaf from exact fi: zero drift
        float v = fmaf(av, fi, bvP);
        float wx = __builtin_amdgcn_fractf(u);
        float wy = __builtin_amdgcn_fractf(v);
        int iu = (int)u, iv = (int)v;    // trunc==floor (coords > 0)
        uint2 q = src[iv * PP + iu];     // 8B aligned: the whole 2x2 footprint
        H2U Pl, Pr;
        Pl.u = q.x; Pr.u = q.y;
        hh2 wyv = cvt_pkrtz(1.0f - wy, wy);
        float mx0 = __builtin_amdgcn_fdot2(wyv, Pl.h, 0.0f, false);
        float mx1 = __builtin_amdgcn_fdot2(wyv, Pr.h, 0.0f, false);
        s = fmaf(wx, mx1 - mx0, s + mx0);
        fi += 8.0f;
    }

    // merge the 8 i-offset partials (lanes dd*8 .. dd*8+7)
    s += __shfl_xor(s, 1);
    s += __shfl_xor(s, 2);
    s += __shfl_xor(s, 4);
    if (ii == 0) out[d * NA + a] = s;    // sole owner of (d,a)
}

extern "C" void kernel_launch(void* const* d_in, const int* in_sizes, int n_in,
                              void* d_out, int out_size, void* d_ws, size_t ws_size,
                              hipStream_t stream) {
    const float* img  = (const float*)d_in[0];
    const int* angles = (const int*)d_in[1];
    float* out = (float*)d_out;
    float* ws  = (float*)d_ws;

    uint2*  imgQ  = (uint2*)(ws + WS_IMGQ);
    uint2*  imgQT = (uint2*)(ws + WS_IMGQT);
    float4* tab   = (float4*)(ws + WS_TAB);
    int*    flags = (int*)(ws + WS_FLAGS);

    dim3 pgrid(22, 22);
    pad_kernel<<<pgrid, 256, 0, stream>>>(img, angles, imgQ, imgQT, tab, flags);

    dim3 grid(N / 32, NA);
    radon_kernel<<<grid, 256, 0, stream>>>(imgQ, imgQT, tab, flags, out);
}

// Round 5
// 92.659 us; speedup vs baseline: 1.2930x; 1.2930x over previous
//
#include <hip/hip_runtime.h>
#include <hip/hip_fp16.h>
#include <stdint.h>

#define N 512
#define NA 180
#define TD 64           // detectors per block
#define TW 96           // LDS tile pitch in pair-dwords
#define NCH 40          // chunks per phase tile (uniform!): 40*256 dw = 107 rows x 96 cols
#define TILE_DW (NCH * 256)         // 10240 dw = 40960 B; x2 buffers = 81920 B -> 2 blocks/CU
#define PP 708          // padded pair-image pitch (dwords)
#define PR 704          // padded pair-image rows
#define POFF 96         // padded index of image row/col 0

// d_ws float-offsets (R0 layout)
#define WS_IMGPB  0
#define WS_IMGTPB (PR * PP)                 // 498432
#define WS_TAB    (2 * PR * PP)             // 996864 (16B aligned)
#define WS_FLAGS  (WS_TAB + 4 * NA)

typedef _Float16 hh2 __attribute__((ext_vector_type(2)));
union H2U { uint32_t u; hh2 h; };

__device__ __forceinline__ hh2 cvt_pkrtz(float a, float b) {
    return __builtin_bit_cast(hh2, __builtin_amdgcn_cvt_pkrtz(a, b));
}

__device__ __forceinline__ uint32_t packh2(float a, float b) {
    __half2 h = __halves2half2(__float2half(a), __float2half(b));
    return *(uint32_t*)&h;
}

__device__ __forceinline__ void load16_to_lds(const uint32_t* g, uint32_t* l) {
    __builtin_amdgcn_global_load_lds(
        (const __attribute__((address_space(1))) void*)g,
        (__attribute__((address_space(3))) void*)l,
        16 /*bytes*/, 0 /*offset*/, 0 /*aux*/);
}

// Tiled pad: 22x22 blocks of 32x32 (484 blocks ~ 2/CU). Builds the padded
// HORIZONTAL fp16-pair image (imgPB[r][c] = (h(P[r][c]), h(P[r][c+1]))) and
// its transpose, plus the per-angle affine table. All accesses coalesced.
__global__ __launch_bounds__(256) void pad_kernel(const float* __restrict__ img,
                                                  const int* __restrict__ angles,
                                                  uint32_t* __restrict__ imgPB,
                                                  uint32_t* __restrict__ imgTPB,
                                                  float4* __restrict__ tab,
                                                  int* __restrict__ flags) {
    __shared__ float lds[33 * 34];   // pitch 34
    const int tid = threadIdx.x;
    const int bx = blockIdx.x, by = blockIdx.y;

    if (bx == 0 && by == 0 && tid < NA) {
        float t = (float)angles[tid] * 0.017453292519943295f;
        float si = sinf(t), co = cosf(t);
        int useT = fabsf(si) > fabsf(co);
        float4 e;
        if (useT) { e.x = co; e.y = -si; e.z = si; e.w = co; }
        else      { e.x = si; e.y = co;  e.z = co; e.w = -si; }
        tab[tid] = e;                // (au, bus, av, bvs)
        flags[tid] = useT;
    }

    // stage 33x33 of the padded image: padded coords (by*32+r, bx*32+c)
    for (int idx = tid; idx < 33 * 33; idx += 256) {
        int r = idx / 33, cc = idx - r * 33;
        int y = by * 32 + r - POFF, x = bx * 32 + cc - POFF;
        bool in = ((unsigned)y < N) && ((unsigned)x < N);
        lds[r * 34 + cc] = in ? img[y * N + x] : 0.0f;
    }
    __syncthreads();
    const int r0 = tid >> 5, cl = tid & 31;
#pragma unroll
    for (int j = 0; j < 4; ++j) {
        int row = j * 8 + r0;
        // horizontal pair of P at (by*32+row, bx*32+cl)
        imgPB[(size_t)(by * 32 + row) * PP + bx * 32 + cl] =
            packh2(lds[row * 34 + cl], lds[row * 34 + cl + 1]);
        // horizontal pair of P^T at (bx*32+row, by*32+cl):
        //   (PT[R][C], PT[R][C+1]) = (P[C][R], P[C+1][R])
        imgTPB[(size_t)(bx * 32 + row) * PP + by * 32 + cl] =
            packh2(lds[cl * 34 + row], lds[(cl + 1) * 34 + row]);
    }
}

// One block = (1 angle, 64 detectors, ALL 512 i), eight 64-i phases.
// T3+T4 pipeline: raw s_barrier + COUNTED vmcnt. Every phase stages a uniform
// 40-chunk (107-row x 96-col) window -> every wave issues exactly 5
// global_load_lds per phase, so after issuing phase p+1's loads,
// s_waitcnt vmcnt(5) guarantees phase p's loads have landed. No vmcnt(0)
// drain until the final phase. Dead phases stage a clamped in-bounds window
// (sampling skipped, block-uniform), keeping the count invariant exact.
//
// Window-bounds proof: live phases have umin in [-90.3, 512], vmin <= 512,
// and per-phase span <= 63*sqrt(2) ~ 89.1. vb = clamp(floor(vmin)-1,-96,501):
// needed rows [floor(vmin)-1, floor(vmax)+1] (vmax <= vmin+89.1 -> top <=
// floor(vmin)+91) fit the 107-row window even when clamped (501+96=597 ..
// 703 covers worst-case 511..604). ub0 = clamp((floor(umin)-1)&~3,-96,516):
// window covers [floor(umin)-1, floor(umin)+91] >= floor(umax)+1. Padded
// indices: rows 0..703, cols 0..707 -- all staging reads in-bounds.
__global__ __launch_bounds__(512, 4) void radon_kernel(const uint32_t* __restrict__ imgPB,
                                                       const uint32_t* __restrict__ imgTPB,
                                                       const float4* __restrict__ tab,
                                                       const int* __restrict__ flags,
                                                       float* __restrict__ out) {
    __shared__ uint32_t tile[2 * TILE_DW];

    const int tid  = threadIdx.x;
    const int lane = tid & 63;
    const int wave = tid >> 6;           // 0..7
    const int d0 = blockIdx.x * TD;
    const int a  = blockIdx.y;
    const int rot = (blockIdx.x + blockIdx.y) & 7;   // de-phase co-resident blocks

    const float c = 255.5f;
    const float4 tb = tab[a];
    const float au = tb.x, bus = tb.y, av = tb.z, bvs = tb.w;

    // d-extremes of the affine offset (fixed for the whole block)
    const float xc0 = (float)d0 - c, xc1 = (float)(d0 + TD - 1) - c;
    const float buA = fmaf(bus, xc0, c), buB = fmaf(bus, xc1, c);
    const float bvA = fmaf(bvs, xc0, c), bvB = fmaf(bvs, xc1, c);
    const float buMin = fminf(buA, buB), buMax = fmaxf(buA, buB);
    const float bvMin = fminf(bvA, bvB), bvMax = fmaxf(bvA, bvB);

    const uint32_t* __restrict__ src = flags[a] ? imgTPB : imgPB;

    // per-lane affine offsets (shared by all phases)
    const float xcl = (float)(d0 + lane) - c;
    const float buLb = fmaf(bus, xcl, c);
    const float bvLb = fmaf(bvs, xcl, c);

    // incremental staging address bases (per lane, shared by all phases)
    const int t0g  = wave * 256 + (lane << 2);   // dword index into tile
    const int q0   = t0g / TW;
    const int c0   = t0g - q0 * TW;
    const int goff0 = q0 * PP + c0;              // dword offset from gbase

    // per-phase params, all 8 upfront (constant indices after unroll -> regs)
    int ub0s[8], vbs[8], lives[8];
#pragma unroll
    for (int p8 = 0; p8 < 8; ++p8) {
        const int ph = (p8 + rot) & 7;
        const int ip = ph * 64;
        const float fi0 = (float)ip - c, fi1 = (float)(ip + 63) - c;
        const float fiLoU = (au >= 0.0f) ? fi0 : fi1, fiHiU = (au >= 0.0f) ? fi1 : fi0;
        const float fiLoV = (av >= 0.0f) ? fi0 : fi1, fiHiV = (av >= 0.0f) ? fi1 : fi0;
        const float umin = fmaf(au, fiLoU, buMin), umax = fmaf(au, fiHiU, buMax);
        const float vmin = fmaf(av, fiLoV, bvMin), vmax = fmaf(av, fiHiV, bvMax);
        lives[p8] = !(umin > (float)N || umax < -1.0f || vmin > (float)N || vmax < -1.0f);
        int ub0 = (((int)floorf(fminf(umin, 1e6f))) - 1) & ~3;
        int vb  = ((int)floorf(fminf(vmin, 1e6f))) - 1;
        ub0s[p8] = min(max(ub0, -96), 516);   // padded col base 0..612 (mult of 4)
        vbs[p8]  = min(max(vb, -96), 501);    // padded row base 0..597
    }

    auto stageTo = [&](int p8, int base) {
        const uint32_t* gb = src + (vbs[p8] + POFF) * PP + (ub0s[p8] + POFF) + goff0;
        uint32_t* lb = &tile[base];
        int cc = c0;
#pragma unroll
        for (int st = 0; st < 5; ++st) {
            load16_to_lds(gb, lb + (st * 8 + wave) * 256);   // chunk st*8+wave < 40 always
            // advance by 2048 tile-dwords = 21 rows + 32 cols (mod 96)
            cc += 32;
            int wrap = (cc >= TW);
            cc = wrap ? cc - TW : cc;
            gb += 21 * PP + 32 + (wrap ? (PP - TW) : 0);
        }
    };

    float s = 0.0f;

    stageTo(0, 0);                        // prologue: phase 0 into buf0
#pragma unroll
    for (int p8 = 0; p8 < 8; ++p8) {
        const int base = (p8 & 1) * TILE_DW;
        if (p8 < 7) stageTo(p8 + 1, base ^ TILE_DW);   // issue next phase's DMA
        // counted wait: 5 newer loads (next phase) may stay in flight
        if (p8 < 7) { asm volatile("s_waitcnt vmcnt(5)" ::: "memory"); }
        else        { asm volatile("s_waitcnt vmcnt(0)" ::: "memory"); }
        __builtin_amdgcn_s_barrier();     // all waves' phase-p loads landed
        if (lives[p8]) {
            const int ph = (p8 + rot) & 7;
            const float buL = buLb - (float)ub0s[p8];   // tile-local fold
            const float bvL = bvLb - (float)vbs[p8];
            const float fiw = (float)(ph * 64 + wave * 8) - c;
            float u = fmaf(au, fiw, buL);
            float v = fmaf(av, fiw, bvL);
            const uint32_t* tl = tile + base;
#pragma unroll
            for (int k = 0; k < 8; ++k) {
                float wx = __builtin_amdgcn_fractf(u);
                float wy = __builtin_amdgcn_fractf(v);
                int iu = (int)u, iv = (int)v;      // trunc == floor (u,v > 0)
                int ai = iv * TW + iu;
                H2U P0, P1;
                P0.u = tl[ai];
                P1.u = tl[ai + TW];                // ds_read2_b32 0/96
                hh2 wy2 = cvt_pkrtz(wy, wy);
                hh2 m   = wy2 * (P1.h - P0.h) + P0.h;   // pk f16 vertical lerp
                hh2 wv  = cvt_pkrtz(1.0f - wx, wx);
                s = __builtin_amdgcn_fdot2(wv, m, s, false);
                u += au;                           // incremental (drift < 1e-4 px)
                v += av;
            }
        }
        __builtin_amdgcn_s_barrier();     // WAR: sampling of buf done before restage
    }

    // ---- merge 8 wave-partials; plain store (sole owner of (d,a)) ----
    float* ft = (float*)tile;
    ft[tid] = s;
    __syncthreads();
    if (tid < 64) {
        float r = ft[tid]       + ft[tid + 64]  + ft[tid + 128] + ft[tid + 192]
                + ft[tid + 256] + ft[tid + 320] + ft[tid + 384] + ft[tid + 448];
        out[(d0 + tid) * NA + a] = r;
    }
}

extern "C" void kernel_launch(void* const* d_in, const int* in_sizes, int n_in,
                              void* d_out, int out_size, void* d_ws, size_t ws_size,
                              hipStream_t stream) {
    const float* img  = (const float*)d_in[0];
    const int* angles = (const int*)d_in[1];
    float* out = (float*)d_out;
    float* ws  = (float*)d_ws;

    uint32_t* imgPB  = (uint32_t*)(ws + WS_IMGPB);
    uint32_t* imgTPB = (uint32_t*)(ws + WS_IMGTPB);
    float4*   tab    = (float4*)(ws + WS_TAB);
    int*      flags  = (int*)(ws + WS_FLAGS);

    dim3 pgrid(22, 22);
    pad_kernel<<<pgrid, 256, 0, stream>>>(img, angles, imgPB, imgTPB, tab, flags);

    dim3 grid(N / TD, NA);
    radon_kernel<<<grid, 512, 0, stream>>>(imgPB, imgTPB, tab, flags, out);
}

// Round 6
// 89.142 us; speedup vs baseline: 1.3441x; 1.0395x over previous
//
#include <hip/hip_runtime.h>
#include <hip/hip_fp16.h>
#include <stdint.h>

#define N 512
#define NA 180
#define TD 64           // detectors per block
#define TW 96           // LDS tile pitch in pair-dwords
#define TILE_DW (36 * 256)          // 9216 dw = 36864 B -> 4 blocks/CU @ 512 thr (32 waves: FULL)
#define PP 708          // padded pair-image pitch (dwords)
#define PR 704          // padded pair-image rows
#define POFF 96         // padded index of image row/col 0

// d_ws float-offsets
#define WS_IMGPB  0
#define WS_IMGTPB (PR * PP)                 // 498432
#define WS_TAB    (2 * PR * PP)             // 996864 (16B aligned)
#define WS_FLAGS  (WS_TAB + 4 * NA)

typedef _Float16 hh2 __attribute__((ext_vector_type(2)));
union H2U { uint32_t u; hh2 h; };

__device__ __forceinline__ hh2 cvt_pkrtz(float a, float b) {
    return __builtin_bit_cast(hh2, __builtin_amdgcn_cvt_pkrtz(a, b));
}

__device__ __forceinline__ uint32_t packh2(float a, float b) {
    __half2 h = __halves2half2(__float2half(a), __float2half(b));
    return *(uint32_t*)&h;
}

__device__ __forceinline__ void load16_to_lds(const uint32_t* g, uint32_t* l) {
    __builtin_amdgcn_global_load_lds(
        (const __attribute__((address_space(1))) void*)g,
        (__attribute__((address_space(3))) void*)l,
        16 /*bytes*/, 0 /*offset*/, 0 /*aux*/);
}

// Tiled pad: 22x22 blocks of 32x32 (484 blocks ~ 2/CU; R0's 121-block version
// was latency-bound at 0.5 blocks/CU). Builds the padded HORIZONTAL fp16-pair
// image (imgPB[r][c] = (h(P[r][c]), h(P[r][c+1]))) and its transpose, plus the
// per-angle affine table. All global accesses coalesced.
__global__ __launch_bounds__(256) void pad_kernel(const float* __restrict__ img,
                                                  const int* __restrict__ angles,
                                                  uint32_t* __restrict__ imgPB,
                                                  uint32_t* __restrict__ imgTPB,
                                                  float4* __restrict__ tab,
                                                  int* __restrict__ flags) {
    __shared__ float lds[33 * 34];   // pitch 34
    const int tid = threadIdx.x;
    const int bx = blockIdx.x, by = blockIdx.y;

    if (bx == 0 && by == 0 && tid < NA) {
        float t = (float)angles[tid] * 0.017453292519943295f;
        float si = sinf(t), co = cosf(t);
        int useT = fabsf(si) > fabsf(co);
        float4 e;
        if (useT) { e.x = co; e.y = -si; e.z = si; e.w = co; }
        else      { e.x = si; e.y = co;  e.z = co; e.w = -si; }
        tab[tid] = e;                // (au, bus, av, bvs)
        flags[tid] = useT;
    }

    // stage 33x33 of the padded image: padded coords (by*32+r, bx*32+c)
    for (int idx = tid; idx < 33 * 33; idx += 256) {
        int r = idx / 33, cc = idx - r * 33;
        int y = by * 32 + r - POFF, x = bx * 32 + cc - POFF;
        bool in = ((unsigned)y < N) && ((unsigned)x < N);
        lds[r * 34 + cc] = in ? img[y * N + x] : 0.0f;
    }
    __syncthreads();
    const int r0 = tid >> 5, cl = tid & 31;
#pragma unroll
    for (int j = 0; j < 4; ++j) {
        int row = j * 8 + r0;
        // horizontal pair of P at (by*32+row, bx*32+cl)
        imgPB[(size_t)(by * 32 + row) * PP + bx * 32 + cl] =
            packh2(lds[row * 34 + cl], lds[row * 34 + cl + 1]);
        // horizontal pair of P^T at (bx*32+row, by*32+cl):
        //   (PT[R][C], PT[R][C+1]) = (P[C][R], P[C+1][R])
        imgTPB[(size_t)(bx * 32 + row) * PP + by * 32 + cl] =
            packh2(lds[cl * 34 + row], lds[(cl + 1) * 34 + row]);
    }
}

// One block = (1 angle, 64 detectors, ALL 512 i): eight phases of (stage
// fp16-pair tile, sample 8 i/wave). R0-proven structure: single 36 KB buffer,
// 4 blocks/CU (full 32-wave occupancy), phase order rotated per block so
// co-resident blocks don't hit their staging drains in lockstep; dead phases
// (block-uniform) skip their barriers entirely. Only change vs R0: dual
// accumulators s0/s1 halve the per-phase fdot2 dependency chain.
__global__ __launch_bounds__(512, 8) void radon_kernel(const uint32_t* __restrict__ imgPB,
                                                       const uint32_t* __restrict__ imgTPB,
                                                       const float4* __restrict__ tab,
                                                       const int* __restrict__ flags,
                                                       float* __restrict__ out) {
    __shared__ uint32_t tile[TILE_DW];

    const int tid  = threadIdx.x;
    const int lane = tid & 63;
    const int wave = tid >> 6;           // 0..7
    const int d0 = blockIdx.x * TD;
    const int a  = blockIdx.y;
    const int rot = (blockIdx.x + blockIdx.y) & 7;   // de-phase co-resident blocks

    const float c = 255.5f;
    const float4 tb = tab[a];
    const float au = tb.x, bus = tb.y, av = tb.z, bvs = tb.w;

    // d-extremes of the affine offset (fixed for the whole block)
    const float xc0 = (float)d0 - c, xc1 = (float)(d0 + TD - 1) - c;
    const float buA = fmaf(bus, xc0, c), buB = fmaf(bus, xc1, c);
    const float bvA = fmaf(bvs, xc0, c), bvB = fmaf(bvs, xc1, c);
    const float buMin = fminf(buA, buB), buMax = fmaxf(buA, buB);
    const float bvMin = fminf(bvA, bvB), bvMax = fmaxf(bvA, bvB);

    const uint32_t* __restrict__ src = flags[a] ? imgTPB : imgPB;

    // per-lane affine offsets (shared by all phases)
    const float xcl = (float)(d0 + lane) - c;
    const float buLb = fmaf(bus, xcl, c);
    const float bvLb = fmaf(bvs, xcl, c);

    // incremental staging address bases (per lane, shared by all phases)
    const int t0g  = wave * 256 + (lane << 2);   // dword index into tile
    const int q0   = t0g / TW;
    const int c0   = t0g - q0 * TW;
    const int goff0 = q0 * PP + c0;              // dword offset from gbase

    float s0 = 0.0f, s1 = 0.0f;
    for (int p8 = 0; p8 < 8; ++p8) {
        const int ph = (p8 + rot) & 7;
        const int ip = ph * 64;
        const float fi0 = (float)ip - c, fi1 = (float)(ip + 63) - c;
        const float fiLoU = (au >= 0.0f) ? fi0 : fi1, fiHiU = (au >= 0.0f) ? fi1 : fi0;
        const float fiLoV = (av >= 0.0f) ? fi0 : fi1, fiHiV = (av >= 0.0f) ? fi1 : fi0;
        const float umin = fmaf(au, fiLoU, buMin), umax = fmaf(au, fiHiU, buMax);
        const float vmin = fmaf(av, fiLoV, bvMin), vmax = fmaf(av, fiHiV, bvMax);
        // block-uniform: skipping barriers is legal (all threads agree)
        if (umin > (float)N || umax < -1.0f || vmin > (float)N || vmax < -1.0f)
            continue;

        // >=1-texel margins; for live phases umin >= -90.3 so cols/rows stay
        // inside the 96-apron (no OOB).
        const int ub0 = (((int)floorf(umin)) - 1) & ~3;
        const int vb  = ((int)floorf(vmin)) - 1;
        // rows touched: vb .. floor(vmax)+2  (bottom ulp margin)
        const int rows = ((int)floorf(vmax)) + 3 - vb;       // <= 94
        const int nch  = (rows * TW + 255) >> 8;             // <= 36, block-uniform

        __syncthreads();                 // WAR: prev live phase sampling done
        {
            const uint32_t* gb = src + (vb + POFF) * PP + (ub0 + POFF) + goff0;
            int cc = c0;
#pragma unroll
            for (int st = 0; st < 5; ++st) {
                int chunk = st * 8 + wave;        // 0..39
                if (chunk < nch) load16_to_lds(gb, &tile[chunk * 256]);
                // advance by 2048 tile-dwords = 21 rows + 32 cols (mod 96)
                cc += 32;
                int wrap = (cc >= TW);
                cc = wrap ? cc - TW : cc;
                gb += 21 * PP + 32 + (wrap ? (PP - TW) : 0);
            }
        }
        __syncthreads();                 // RAW: staging visible
        {
            const float buL = buLb - (float)ub0;   // tile-local fold
            const float bvL = bvLb - (float)vb;
            const float fiw = (float)(ip + wave * 8) - c;
            float u = fmaf(au, fiw, buL);
            float v = fmaf(av, fiw, bvL);
#pragma unroll
            for (int k = 0; k < 8; ++k) {
                float wx = __builtin_amdgcn_fractf(u);
                float wy = __builtin_amdgcn_fractf(v);
                int iu = (int)u, iv = (int)v;      // trunc == floor (u,v > 0)
                int ai = iv * TW + iu;
                H2U P0, P1;
                P0.u = tile[ai];
                P1.u = tile[ai + TW];              // ds_read2_b32 0/96
                hh2 wy2 = cvt_pkrtz(wy, wy);
                hh2 m   = wy2 * (P1.h - P0.h) + P0.h;   // pk f16 vertical lerp
                hh2 wv  = cvt_pkrtz(1.0f - wx, wx);
                if (k & 1) s1 = __builtin_amdgcn_fdot2(wv, m, s1, false);
                else       s0 = __builtin_amdgcn_fdot2(wv, m, s0, false);
                u += au;                           // incremental (drift < 1e-4 px)
                v += av;
            }
        }
    }
    float s = s0 + s1;

    // ---- merge 8 wave-partials; plain store (sole owner of (d,a)) ----
    __syncthreads();
    float* ft = (float*)tile;
    ft[tid] = s;
    __syncthreads();
    if (tid < 64) {
        float r = ft[tid]       + ft[tid + 64]  + ft[tid + 128] + ft[tid + 192]
                + ft[tid + 256] + ft[tid + 320] + ft[tid + 384] + ft[tid + 448];
        out[(d0 + tid) * NA + a] = r;
    }
}

extern "C" void kernel_launch(void* const* d_in, const int* in_sizes, int n_in,
                              void* d_out, int out_size, void* d_ws, size_t ws_size,
                              hipStream_t stream) {
    const float* img  = (const float*)d_in[0];
    const int* angles = (const int*)d_in[1];
    float* out = (float*)d_out;
    float* ws  = (float*)d_ws;

    uint32_t* imgPB  = (uint32_t*)(ws + WS_IMGPB);
    uint32_t* imgTPB = (uint32_t*)(ws + WS_IMGTPB);
    float4*   tab    = (float4*)(ws + WS_TAB);
    int*      flags  = (int*)(ws + WS_FLAGS);

    dim3 pgrid(22, 22);
    pad_kernel<<<pgrid, 256, 0, stream>>>(img, angles, imgPB, imgTPB, tab, flags);

    dim3 grid(N / TD, NA);
    radon_kernel<<<grid, 512, 0, stream>>>(imgPB, imgTPB, tab, flags, out);
}